// Round 1
// baseline (1215.573 us; speedup 1.0000x reference)
//
#include <hip/hip_runtime.h>
#include <hip/hip_bf16.h>
#include <stdint.h>

typedef __bf16 bf16_t;
typedef __bf16 bf16x4 __attribute__((ext_vector_type(4)));
typedef __bf16 bf16x8 __attribute__((ext_vector_type(8)));
typedef float f32x4 __attribute__((ext_vector_type(4)));

#define LOG2E 1.44269504088896340736f

// ---------------- f32 -> bf16 convert (float4 vectorized) ----------------
__global__ void cvt_f32_bf16(const float* __restrict__ in, bf16_t* __restrict__ out, int n4) {
  int i = blockIdx.x * blockDim.x + threadIdx.x;
  if (i >= n4) return;
  float4 v = ((const float4*)in)[i];
  bf16x4 o = { (bf16_t)v.x, (bf16_t)v.y, (bf16_t)v.z, (bf16_t)v.w };
  *(bf16x4*)(out + (size_t)i * 4) = o;
}

// ---------------- async global->LDS, 16B per lane ----------------
__device__ __forceinline__ void async_load16(const bf16_t* g, bf16_t* l) {
#if __has_builtin(__builtin_amdgcn_global_load_lds)
  __builtin_amdgcn_global_load_lds((const __attribute__((address_space(1))) void*)g,
                                   (__attribute__((address_space(3))) void*)l, 16, 0, 0);
#else
  *(bf16x8*)l = *(const bf16x8*)g;
#endif
}

// ---------------- GEMM: C[M,N] = A[M,K] @ B[N,K]^T  (m97 structure) ----------------
// 128x128 tile, 4 waves (2x2), BK=32, 16x16x32 bf16 MFMA.
template<bool F32OUT>
__global__ __launch_bounds__(256) void gemm_bt(const bf16_t* __restrict__ A,
                                               const bf16_t* __restrict__ B,
                                               void* __restrict__ C,
                                               int M, int N, int K) {
  __shared__ bf16_t Alds[128 * 32];
  __shared__ bf16_t Blds[128 * 32];
  const int tid = threadIdx.x;
  const int wave = tid >> 6, lane = tid & 63;
  const int lrow = lane & 15, quad = lane >> 4;
  const int wr = wave >> 1, wc = wave & 1;
  const int bm = blockIdx.y, bn = blockIdx.x;
  const bf16_t* Ab = A + (size_t)bm * 128 * K;
  const bf16_t* Bb = B + (size_t)bn * 128 * K;
  const int r0 = tid >> 2;            // 0..63
  const int c0 = (tid & 3) << 3;      // 0,8,16,24 elements
  f32x4 acc[4][4] = {};

  for (int kk = 0; kk < K; kk += 32) {
    async_load16(Ab + (size_t)r0 * K + kk + c0,        &Alds[tid * 8]);
    async_load16(Ab + (size_t)(r0 + 64) * K + kk + c0, &Alds[(tid + 256) * 8]);
    async_load16(Bb + (size_t)r0 * K + kk + c0,        &Blds[tid * 8]);
    async_load16(Bb + (size_t)(r0 + 64) * K + kk + c0, &Blds[(tid + 256) * 8]);
    __syncthreads();
    bf16x8 af[4], bfv[4];
#pragma unroll
    for (int mt = 0; mt < 4; ++mt)
      af[mt] = *(const bf16x8*)&Alds[(wr * 64 + mt * 16 + lrow) * 32 + quad * 8];
#pragma unroll
    for (int nt = 0; nt < 4; ++nt)
      bfv[nt] = *(const bf16x8*)&Blds[(wc * 64 + nt * 16 + lrow) * 32 + quad * 8];
#pragma unroll
    for (int mt = 0; mt < 4; ++mt)
#pragma unroll
      for (int nt = 0; nt < 4; ++nt)
        acc[mt][nt] = __builtin_amdgcn_mfma_f32_16x16x32_bf16(af[mt], bfv[nt], acc[mt][nt], 0, 0, 0);
    __syncthreads();
  }

#pragma unroll
  for (int mt = 0; mt < 4; ++mt)
#pragma unroll
    for (int nt = 0; nt < 4; ++nt)
#pragma unroll
      for (int r = 0; r < 4; ++r) {
        int row = bm * 128 + wr * 64 + mt * 16 + quad * 4 + r;
        int col = bn * 128 + wc * 64 + nt * 16 + lrow;
        if (F32OUT) ((float*)C)[(size_t)row * N + col] = acc[mt][nt][r];
        else        ((bf16_t*)C)[(size_t)row * N + col] = (bf16_t)acc[mt][nt][r];
      }
}

// ---------------- RoPE (in-place on bf16 buffer, layout (rows, nheads, 128)) ----------------
// thread i -> (row, h, d<64); t = row % 2048; freqs (T,64,2) fp32.
__global__ void rope_kernel(bf16_t* __restrict__ X, const float* __restrict__ F, int hshift) {
  int i = blockIdx.x * blockDim.x + threadIdx.x;
  int d = i & 63;
  int h = (i >> 6) & ((1 << hshift) - 1);
  int row = i >> (6 + hshift);
  int t = row & 2047;
  float c = F[t * 128 + d * 2];
  float s = F[t * 128 + d * 2 + 1];
  size_t base = ((size_t)row << (7 + hshift)) + h * 128 + d;
  float q0 = (float)X[base];
  float q1 = (float)X[base + 64];
  X[base]      = (bf16_t)(q0 * c - q1 * s);
  X[base + 64] = (bf16_t)(q1 * c + q0 * s);
}

// ---------------- Flash attention, causal, GQA 16q/4kv, D=128 ----------------
// grid: x = T/128 (q tile), y = B*NH. 4 waves; wave handles 32 q rows.
// Q held in registers as A-frags (scale folded). K staged [64][136], V transposed [128(d)][72(k)].
// P round-trips through per-wave LDS (C-layout -> A-layout).
__global__ __launch_bounds__(256) void attn_kernel(const bf16_t* __restrict__ Q,
                                                   const bf16_t* __restrict__ K,
                                                   const bf16_t* __restrict__ V,
                                                   bf16_t* __restrict__ O) {
  __shared__ bf16_t Ks[64 * 136];
  __shared__ bf16_t Vs[128 * 72];
  __shared__ bf16_t Ps[4 * 32 * 72];
  const int tid = threadIdx.x;
  const int wave = tid >> 6, lane = tid & 63;
  const int lrow = lane & 15, quad = lane >> 4;
  const int qt = blockIdx.x;
  const int bh = blockIdx.y;
  const int b = bh >> 4, h = bh & 15, kvh = h >> 2;
  const size_t qoff = ((size_t)b * 2048) * 2048 + (size_t)h * 128;
  const size_t koff = ((size_t)b * 2048) * 512 + (size_t)kvh * 128;

  // Q fragments (A-layout), softmax scale folded in
  bf16x8 qf[2][4];
  const float scale = 0.08838834764831845f;  // 1/sqrt(128)
#pragma unroll
  for (int mt = 0; mt < 2; ++mt) {
    int qrow = qt * 128 + wave * 32 + mt * 16 + lrow;
    const bf16_t* qp = Q + qoff + (size_t)qrow * 2048 + quad * 8;
#pragma unroll
    for (int ks = 0; ks < 4; ++ks) {
      bf16x8 v = *(const bf16x8*)(qp + ks * 32);
      bf16x8 sv;
#pragma unroll
      for (int j = 0; j < 8; ++j) sv[j] = (bf16_t)((float)v[j] * scale);
      qf[mt][ks] = sv;
    }
  }

  f32x4 Oacc[2][8] = {};
  float mstate[2][4], lstate[2][4];
#pragma unroll
  for (int mt = 0; mt < 2; ++mt)
#pragma unroll
    for (int r = 0; r < 4; ++r) { mstate[mt][r] = -3.0e38f; lstate[mt][r] = 0.f; }

  const int vd = tid & 127;          // d for V transpose
  const int vk0 = (tid >> 7) * 8;    // key chunk base
  const int kt_end = 2 * qt + 2;

  for (int kt = 0; kt < kt_end; ++kt) {
    __syncthreads();  // previous iter's LDS reads drained
    // stage K tile [64 keys][128 d] -> Ks stride 136
#pragma unroll
    for (int c = 0; c < 4; ++c) {
      int idx = c * 256 + tid;
      int row = idx >> 4, col0 = (idx & 15) << 3;
      *(bf16x8*)&Ks[row * 136 + col0] =
          *(const bf16x8*)(K + koff + (size_t)(kt * 64 + row) * 512 + col0);
    }
    // stage V transposed: Vs[d][k], stride 72
#pragma unroll
    for (int c = 0; c < 4; ++c) {
      int k0 = vk0 + c * 16;
      bf16x8 col;
#pragma unroll
      for (int j = 0; j < 8; ++j)
        col[j] = V[koff + (size_t)(kt * 64 + k0 + j) * 512 + vd];
      *(bf16x8*)&Vs[vd * 72 + k0] = col;
    }
    __syncthreads();

    if (kt * 64 <= qt * 128 + wave * 32 + 31) {  // wave-uniform skip of fully-masked tiles
      // S = Q K^T (C-layout: col=key=lane&15, row=q=quad*4+reg)
      f32x4 S[2][4] = {};
#pragma unroll
      for (int ks = 0; ks < 4; ++ks) {
        bf16x8 bk[4];
#pragma unroll
        for (int nt = 0; nt < 4; ++nt)
          bk[nt] = *(const bf16x8*)&Ks[(nt * 16 + lrow) * 136 + ks * 32 + quad * 8];
#pragma unroll
        for (int mt = 0; mt < 2; ++mt)
#pragma unroll
          for (int nt = 0; nt < 4; ++nt)
            S[mt][nt] = __builtin_amdgcn_mfma_f32_16x16x32_bf16(qf[mt][ks], bk[nt], S[mt][nt], 0, 0, 0);
      }
      // causal mask (diagonal tiles only)
      if (kt * 64 + 63 > qt * 128 + wave * 32) {
#pragma unroll
        for (int mt = 0; mt < 2; ++mt) {
          int qrow0 = qt * 128 + wave * 32 + mt * 16 + quad * 4;
#pragma unroll
          for (int nt = 0; nt < 4; ++nt) {
            int kcol = kt * 64 + nt * 16 + lrow;
#pragma unroll
            for (int r = 0; r < 4; ++r)
              if (kcol > qrow0 + r) S[mt][nt][r] = -3.0e38f;
          }
        }
      }
      // online softmax; rows live across 16 lanes of a quad
#pragma unroll
      for (int mt = 0; mt < 2; ++mt) {
        float al[4];
#pragma unroll
        for (int r = 0; r < 4; ++r) {
          float mx = fmaxf(fmaxf(S[mt][0][r], S[mt][1][r]), fmaxf(S[mt][2][r], S[mt][3][r]));
          mx = fmaxf(mx, __shfl_xor(mx, 1, 16));
          mx = fmaxf(mx, __shfl_xor(mx, 2, 16));
          mx = fmaxf(mx, __shfl_xor(mx, 4, 16));
          mx = fmaxf(mx, __shfl_xor(mx, 8, 16));
          float mnew = fmaxf(mstate[mt][r], mx);
          al[r] = exp2f((mstate[mt][r] - mnew) * LOG2E);
          mstate[mt][r] = mnew;
          float rs = 0.f;
#pragma unroll
          for (int nt = 0; nt < 4; ++nt) {
            float p0 = exp2f((S[mt][nt][r] - mnew) * LOG2E);
            S[mt][nt][r] = p0;
            rs += p0;
          }
          rs += __shfl_xor(rs, 1, 16);
          rs += __shfl_xor(rs, 2, 16);
          rs += __shfl_xor(rs, 4, 16);
          rs += __shfl_xor(rs, 8, 16);
          lstate[mt][r] = lstate[mt][r] * al[r] + rs;
        }
        // P -> Ps (per-wave region), rescale O
#pragma unroll
        for (int nt = 0; nt < 4; ++nt)
#pragma unroll
          for (int r = 0; r < 4; ++r)
            Ps[wave * 2304 + (mt * 16 + quad * 4 + r) * 72 + nt * 16 + lrow] = (bf16_t)S[mt][nt][r];
#pragma unroll
        for (int dt = 0; dt < 8; ++dt)
#pragma unroll
          for (int r = 0; r < 4; ++r)
            Oacc[mt][dt][r] *= al[r];
      }
      // O += P V  (A-frags from Ps, B-frags from transposed Vs); same-wave LDS RAW,
      // compiler inserts lgkmcnt wait — no barrier needed (Ps regions are wave-private).
#pragma unroll
      for (int ks2 = 0; ks2 < 2; ++ks2) {
        bf16x8 ap[2];
#pragma unroll
        for (int mt = 0; mt < 2; ++mt)
          ap[mt] = *(const bf16x8*)&Ps[wave * 2304 + (mt * 16 + lrow) * 72 + ks2 * 32 + quad * 8];
#pragma unroll
        for (int dt = 0; dt < 8; ++dt) {
          bf16x8 bv = *(const bf16x8*)&Vs[(dt * 16 + lrow) * 72 + ks2 * 32 + quad * 8];
#pragma unroll
          for (int mt = 0; mt < 2; ++mt)
            Oacc[mt][dt] = __builtin_amdgcn_mfma_f32_16x16x32_bf16(ap[mt], bv, Oacc[mt][dt], 0, 0, 0);
        }
      }
    }
  }

  // epilogue: O /= l, store bf16
#pragma unroll
  for (int mt = 0; mt < 2; ++mt) {
    float linv[4];
#pragma unroll
    for (int r = 0; r < 4; ++r) linv[r] = 1.0f / lstate[mt][r];
#pragma unroll
    for (int dt = 0; dt < 8; ++dt)
#pragma unroll
      for (int r = 0; r < 4; ++r) {
        int row = qt * 128 + wave * 32 + mt * 16 + quad * 4 + r;
        int col = dt * 16 + lrow;
        O[qoff + (size_t)row * 2048 + col] = (bf16_t)(Oacc[mt][dt][r] * linv[r]);
      }
  }
}

// ---------------- launch ----------------
extern "C" void kernel_launch(void* const* d_in, const int* in_sizes, int n_in,
                              void* d_out, int out_size, void* d_ws, size_t ws_size,
                              hipStream_t stream) {
  const float* x  = (const float*)d_in[0];
  const float* fc = (const float*)d_in[1];
  const float* Wq = (const float*)d_in[2];
  const float* Wk = (const float*)d_in[3];
  const float* Wv = (const float*)d_in[4];
  const float* Wo = (const float*)d_in[5];
  float* out = (float*)d_out;

  char* ws = (char*)d_ws;
  size_t off = 0;
  auto alloc = [&](size_t bytes) { char* p = ws + off; off += bytes; return p; };
  bf16_t* xb  = (bf16_t*)alloc((size_t)8192 * 2048 * 2);
  bf16_t* Wqb = (bf16_t*)alloc((size_t)2048 * 2048 * 2);
  bf16_t* Wkb = (bf16_t*)alloc((size_t)512 * 2048 * 2);
  bf16_t* Wvb = (bf16_t*)alloc((size_t)512 * 2048 * 2);
  bf16_t* Wob = (bf16_t*)alloc((size_t)2048 * 2048 * 2);
  bf16_t* Qb  = (bf16_t*)alloc((size_t)8192 * 2048 * 2);
  bf16_t* Kb  = (bf16_t*)alloc((size_t)8192 * 512 * 2);
  bf16_t* Vb  = (bf16_t*)alloc((size_t)8192 * 512 * 2);
  bf16_t* Ab  = (bf16_t*)alloc((size_t)8192 * 2048 * 2);
  (void)ws_size; (void)in_sizes; (void)n_in; (void)out_size;

  cvt_f32_bf16<<<16384, 256, 0, stream>>>(x,  xb,  4194304);
  cvt_f32_bf16<<<4096,  256, 0, stream>>>(Wq, Wqb, 1048576);
  cvt_f32_bf16<<<1024,  256, 0, stream>>>(Wk, Wkb, 262144);
  cvt_f32_bf16<<<1024,  256, 0, stream>>>(Wv, Wvb, 262144);
  cvt_f32_bf16<<<4096,  256, 0, stream>>>(Wo, Wob, 1048576);

  dim3 gq(16, 64), gk(4, 64);
  gemm_bt<false><<<gq, 256, 0, stream>>>(xb, Wqb, Qb, 8192, 2048, 2048);
  gemm_bt<false><<<gk, 256, 0, stream>>>(xb, Wkb, Kb, 8192, 512, 2048);
  gemm_bt<false><<<gk, 256, 0, stream>>>(xb, Wvb, Vb, 8192, 512, 2048);

  rope_kernel<<<32768, 256, 0, stream>>>(Qb, fc, 4);  // Q: 16 heads
  rope_kernel<<<8192,  256, 0, stream>>>(Kb, fc, 2);  // K: 4 heads

  dim3 ga(16, 64);
  attn_kernel<<<ga, 256, 0, stream>>>(Qb, Kb, Vb, Ab);

  gemm_bt<true><<<gq, 256, 0, stream>>>(Ab, Wob, out, 8192, 2048, 2048);
}

// Round 2
// 547.074 us; speedup vs baseline: 2.2220x; 2.2220x over previous
//
#include <hip/hip_runtime.h>
#include <hip/hip_bf16.h>
#include <stdint.h>

typedef __bf16 bf16_t;
typedef __bf16 bf16x4 __attribute__((ext_vector_type(4)));
typedef __bf16 bf16x8 __attribute__((ext_vector_type(8)));
typedef float f32x4 __attribute__((ext_vector_type(4)));

__device__ __forceinline__ float fast_exp2(float x) {
#if __has_builtin(__builtin_amdgcn_exp2f)
  return __builtin_amdgcn_exp2f(x);
#else
  return exp2f(x);
#endif
}

// ---------------- f32 -> bf16 convert (float4 vectorized) ----------------
__global__ void cvt_f32_bf16(const float* __restrict__ in, bf16_t* __restrict__ out, int n4) {
  int i = blockIdx.x * blockDim.x + threadIdx.x;
  if (i >= n4) return;
  float4 v = ((const float4*)in)[i];
  bf16x4 o = { (bf16_t)v.x, (bf16_t)v.y, (bf16_t)v.z, (bf16_t)v.w };
  *(bf16x4*)(out + (size_t)i * 4) = o;
}

// ---------------- async global->LDS, 16B per lane ----------------
__device__ __forceinline__ void async_load16(const bf16_t* g, bf16_t* l) {
#if __has_builtin(__builtin_amdgcn_global_load_lds)
  __builtin_amdgcn_global_load_lds((const __attribute__((address_space(1))) void*)g,
                                   (__attribute__((address_space(3))) void*)l, 16, 0, 0);
#else
  *(bf16x8*)l = *(const bf16x8*)g;
#endif
}

// ---------------- GEMM: C[M,N] = A[M,K] @ B[N,K]^T  (m97 structure) ----------------
template<bool F32OUT>
__global__ __launch_bounds__(256) void gemm_bt(const bf16_t* __restrict__ A,
                                               const bf16_t* __restrict__ B,
                                               void* __restrict__ C,
                                               int M, int N, int K) {
  __shared__ bf16_t Alds[128 * 32];
  __shared__ bf16_t Blds[128 * 32];
  const int tid = threadIdx.x;
  const int wave = tid >> 6, lane = tid & 63;
  const int lrow = lane & 15, quad = lane >> 4;
  const int wr = wave >> 1, wc = wave & 1;
  const int bm = blockIdx.y, bn = blockIdx.x;
  const bf16_t* Ab = A + (size_t)bm * 128 * K;
  const bf16_t* Bb = B + (size_t)bn * 128 * K;
  const int r0 = tid >> 2;
  const int c0 = (tid & 3) << 3;
  f32x4 acc[4][4] = {};

  for (int kk = 0; kk < K; kk += 32) {
    async_load16(Ab + (size_t)r0 * K + kk + c0,        &Alds[tid * 8]);
    async_load16(Ab + (size_t)(r0 + 64) * K + kk + c0, &Alds[(tid + 256) * 8]);
    async_load16(Bb + (size_t)r0 * K + kk + c0,        &Blds[tid * 8]);
    async_load16(Bb + (size_t)(r0 + 64) * K + kk + c0, &Blds[(tid + 256) * 8]);
    __syncthreads();
    bf16x8 af[4], bfv[4];
#pragma unroll
    for (int mt = 0; mt < 4; ++mt)
      af[mt] = *(const bf16x8*)&Alds[(wr * 64 + mt * 16 + lrow) * 32 + quad * 8];
#pragma unroll
    for (int nt = 0; nt < 4; ++nt)
      bfv[nt] = *(const bf16x8*)&Blds[(wc * 64 + nt * 16 + lrow) * 32 + quad * 8];
#pragma unroll
    for (int mt = 0; mt < 4; ++mt)
#pragma unroll
      for (int nt = 0; nt < 4; ++nt)
        acc[mt][nt] = __builtin_amdgcn_mfma_f32_16x16x32_bf16(af[mt], bfv[nt], acc[mt][nt], 0, 0, 0);
    __syncthreads();
  }

#pragma unroll
  for (int mt = 0; mt < 4; ++mt)
#pragma unroll
    for (int nt = 0; nt < 4; ++nt)
#pragma unroll
      for (int r = 0; r < 4; ++r) {
        int row = bm * 128 + wr * 64 + mt * 16 + quad * 4 + r;
        int col = bn * 128 + wc * 64 + nt * 16 + lrow;
        if (F32OUT) ((float*)C)[(size_t)row * N + col] = acc[mt][nt][r];
        else        ((bf16_t*)C)[(size_t)row * N + col] = (bf16_t)acc[mt][nt][r];
      }
}

// ---------------- RoPE (in-place, layout (rows, nheads, 128), row stride param) ----------
__global__ void rope_kernel(bf16_t* __restrict__ X, const float* __restrict__ F,
                            int hshift, int stride) {
  int i = blockIdx.x * blockDim.x + threadIdx.x;
  int d = i & 63;
  int h = (i >> 6) & ((1 << hshift) - 1);
  int row = i >> (6 + hshift);
  int t = row & 2047;
  float c = F[t * 128 + d * 2];
  float s = F[t * 128 + d * 2 + 1];
  size_t base = (size_t)row * stride + h * 128 + d;
  float q0 = (float)X[base];
  float q1 = (float)X[base + 64];
  X[base]      = (bf16_t)(q0 * c - q1 * s);
  X[base + 64] = (bf16_t)(q1 * c + q0 * s);
}

// ---------------- V transpose: KV[t][512 + kvh*128 + d] -> Vt[(b*4+kvh)*128+d][t(2048)] ----
__global__ __launch_bounds__(256) void transpose_v(const bf16_t* __restrict__ KV,
                                                   bf16_t* __restrict__ Vt) {
  __shared__ bf16_t tile[64][72];
  const int tid = threadIdx.x;
  const int t0 = blockIdx.x * 64;
  const int c0 = blockIdx.y * 64;
#pragma unroll
  for (int p = 0; p < 4; ++p) {
    int idx = p * 256 + tid;
    int r = idx >> 4, c4 = (idx & 15) * 4;
    *(bf16x4*)&tile[r][c4] = *(const bf16x4*)&KV[(size_t)(t0 + r) * 1024 + 512 + c0 + c4];
  }
  __syncthreads();
  const int bb = t0 >> 11, t0b = t0 & 2047;
#pragma unroll
  for (int p = 0; p < 4; ++p) {
    int idx = p * 256 + tid;
    int cr = idx >> 4, t4 = (idx & 15) * 4;
    int c = c0 + cr;
    int R = (bb * 4 + (c >> 7)) * 128 + (c & 127);
    bf16x4 o;
#pragma unroll
    for (int j = 0; j < 4; ++j) o[j] = tile[t4 + j][cr];
    *(bf16x4*)&Vt[(size_t)R * 2048 + t0b + t4] = o;
  }
}

// ---------------- Flash attention, causal, GQA 16q/4kv, D=128 ----------------
// S^T form: mfma(A=K, B=Q) -> S^T[key][q], softmax rows reduce across quads (2 shuffles).
// P^T written packed (b64) to LDS in natural [q][key]; PV: mfma(A=P, B=V^T) -> O natural.
// K and V^T staged via global_load_lds w=16 with XOR chunk swizzle (conflict-free, no pad).
// Blocks pair q-tiles (qt, 15-qt): every block does exactly 36 K-tile iterations.
__global__ __launch_bounds__(256, 2) void attn_kernel(const bf16_t* __restrict__ Q,
                                                      const bf16_t* __restrict__ KV,
                                                      const bf16_t* __restrict__ Vt,
                                                      bf16_t* __restrict__ O) {
  __shared__ bf16_t Ks[64 * 128];   // [key][d], chunk-swizzled
  __shared__ bf16_t Vs[128 * 64];   // [d][key], chunk-swizzled
  __shared__ bf16_t Ps[4 * 32 * 72];
  const int tid = threadIdx.x;
  const int wave = tid >> 6, lane = tid & 63;
  const int lrow = lane & 15, quad = lane >> 4;
  const int bh = blockIdx.y, b = bh >> 4, h = bh & 15, kvh = h >> 2;
  const size_t qoff  = ((size_t)b * 2048) * 2048 + (size_t)h * 128;
  const size_t koff  = ((size_t)b * 2048) * 1024 + (size_t)kvh * 128;
  const size_t vtoff = ((size_t)(b * 4 + kvh) * 128) * 2048;
  const float qsc = 0.08838834764831845f * 1.44269504088896340736f;  // 1/sqrt(128) * log2(e)
  bf16_t* Pw = Ps + wave * (32 * 72);

  // loop-invariant staging indices
  const int krow_l = tid >> 4;                              // 0..15 (local key row per pass)
  const int kdc    = (tid & 15) ^ (krow_l & 7);             // K chunk swizzle
  const int vrow_l = tid >> 3;                              // 0..31 (local d row per pass)
  const int vkc    = (tid & 7) ^ (vrow_l & 7);              // V chunk swizzle

  for (int phase = 0; phase < 2; ++phase) {
    const int qt = phase ? (15 - blockIdx.x) : blockIdx.x;
    const int qbase = qt * 128 + wave * 32;

    // Q B-frags (scale*log2e folded in): B[n=q][k=d]
    bf16x8 qf[2][4];
#pragma unroll
    for (int nt2 = 0; nt2 < 2; ++nt2) {
      const bf16_t* qp = Q + qoff + (size_t)(qbase + nt2 * 16 + lrow) * 2048 + quad * 8;
#pragma unroll
      for (int ks = 0; ks < 4; ++ks) {
        bf16x8 v = *(const bf16x8*)(qp + ks * 32);
        bf16x8 sv;
#pragma unroll
        for (int j = 0; j < 8; ++j) sv[j] = (bf16_t)((float)v[j] * qsc);
        qf[nt2][ks] = sv;
      }
    }

    f32x4 Oacc[2][8] = {};
    float m_r[2] = {-1.0e30f, -1.0e30f};
    float l_r[2] = {0.f, 0.f};
    const int kt_end = 2 * qt + 2;

    for (int kt = 0; kt < kt_end; ++kt) {
      __syncthreads();  // previous tile's LDS reads drained
      const bf16_t* Kg = KV + koff + (size_t)(kt * 64) * 1024;
      const bf16_t* Vg = Vt + vtoff + kt * 64;
#pragma unroll
      for (int c4 = 0; c4 < 4; ++c4) {
        int ci = c4 * 256 + tid;
        async_load16(Kg + (size_t)(c4 * 16 + krow_l) * 1024 + kdc * 8, &Ks[ci * 8]);
        async_load16(Vg + (size_t)(c4 * 32 + vrow_l) * 2048 + vkc * 8, &Vs[ci * 8]);
      }
      __syncthreads();  // staging complete

      if (kt * 64 <= qbase + 31) {  // wave-uniform skip of fully-masked tiles
        // S^T = K Q^T : C[m=key][n=q]
        f32x4 S[2][4] = {};
#pragma unroll
        for (int ks = 0; ks < 4; ++ks) {
          bf16x8 kf[4];
#pragma unroll
          for (int mt = 0; mt < 4; ++mt) {
            int dc = (ks * 4 + quad) ^ (lrow & 7);
            kf[mt] = *(const bf16x8*)&Ks[(mt * 16 + lrow) * 128 + dc * 8];
          }
#pragma unroll
          for (int nt2 = 0; nt2 < 2; ++nt2)
#pragma unroll
            for (int mt = 0; mt < 4; ++mt)
              S[nt2][mt] = __builtin_amdgcn_mfma_f32_16x16x32_bf16(kf[mt], qf[nt2][ks], S[nt2][mt], 0, 0, 0);
        }
        // causal mask (diagonal tiles only). S^T element: key=row, q=col.
        if (kt * 64 + 63 > qbase) {
#pragma unroll
          for (int nt2 = 0; nt2 < 2; ++nt2) {
            int q = qbase + nt2 * 16 + lrow;
#pragma unroll
            for (int mt = 0; mt < 4; ++mt) {
              int key0 = kt * 64 + mt * 16 + quad * 4;
#pragma unroll
              for (int r = 0; r < 4; ++r)
                if (key0 + r > q) S[nt2][mt][r] = -1.0e30f;
            }
          }
        }
        // online softmax: thread's rows are q = qbase + nt2*16 + lrow (log2 domain)
        float alpha[2];
#pragma unroll
        for (int nt2 = 0; nt2 < 2; ++nt2) {
          float mx = -1.0e30f;
#pragma unroll
          for (int mt = 0; mt < 4; ++mt)
#pragma unroll
            for (int r = 0; r < 4; ++r) mx = fmaxf(mx, S[nt2][mt][r]);
          mx = fmaxf(mx, __shfl_xor(mx, 16, 64));
          mx = fmaxf(mx, __shfl_xor(mx, 32, 64));
          float mnew = fmaxf(m_r[nt2], mx);
          alpha[nt2] = fast_exp2(m_r[nt2] - mnew);
          m_r[nt2] = mnew;
          float rs = 0.f;
#pragma unroll
          for (int mt = 0; mt < 4; ++mt) {
            bf16x4 pk;
#pragma unroll
            for (int r = 0; r < 4; ++r) {
              float p = fast_exp2(S[nt2][mt][r] - mnew);
              rs += p;
              pk[r] = (bf16_t)p;
            }
            // P natural [q][key]: 4 consecutive keys packed -> one b64 write
            *(bf16x4*)&Pw[(nt2 * 16 + lrow) * 72 + mt * 16 + quad * 4] = pk;
          }
          rs += __shfl_xor(rs, 16, 64);
          rs += __shfl_xor(rs, 32, 64);
          l_r[nt2] = l_r[nt2] * alpha[nt2] + rs;
        }
        // lazy O rescale (alpha==1 once running max stabilizes)
        bool nz = (alpha[0] != 1.f) || (alpha[1] != 1.f);
        if (__ballot(nz) != 0ull) {
#pragma unroll
          for (int mt2 = 0; mt2 < 2; ++mt2)
#pragma unroll
            for (int r = 0; r < 4; ++r) {
              float av = __shfl(alpha[mt2], quad * 4 + r, 16);
#pragma unroll
              for (int dt = 0; dt < 8; ++dt) Oacc[mt2][dt][r] *= av;
            }
        }
        // O += P V : A=P from Pw (b128), B=V^T from Vs (swizzled)
#pragma unroll
        for (int ks2 = 0; ks2 < 2; ++ks2) {
          bf16x8 ap[2];
#pragma unroll
          for (int mt2 = 0; mt2 < 2; ++mt2)
            ap[mt2] = *(const bf16x8*)&Pw[(mt2 * 16 + lrow) * 72 + ks2 * 32 + quad * 8];
          int dc = (ks2 * 4 + quad) ^ (lrow & 7);
#pragma unroll
          for (int dt = 0; dt < 8; ++dt) {
            bf16x8 bv = *(const bf16x8*)&Vs[(dt * 16 + lrow) * 64 + dc * 8];
#pragma unroll
            for (int mt2 = 0; mt2 < 2; ++mt2)
              Oacc[mt2][dt] = __builtin_amdgcn_mfma_f32_16x16x32_bf16(ap[mt2], bv, Oacc[mt2][dt], 0, 0, 0);
          }
        }
      }
    }

    // epilogue: O /= l (l fetched per output row via shuffle), store bf16
#pragma unroll
    for (int mt2 = 0; mt2 < 2; ++mt2)
#pragma unroll
      for (int r = 0; r < 4; ++r) {
        float lv = __shfl(l_r[mt2], quad * 4 + r, 16);
        float inv = 1.0f / lv;
        int row = qbase + mt2 * 16 + quad * 4 + r;
#pragma unroll
        for (int dt = 0; dt < 8; ++dt)
          O[qoff + (size_t)row * 2048 + dt * 16 + lrow] = (bf16_t)(Oacc[mt2][dt][r] * inv);
      }
  }
}

// ---------------- launch ----------------
extern "C" void kernel_launch(void* const* d_in, const int* in_sizes, int n_in,
                              void* d_out, int out_size, void* d_ws, size_t ws_size,
                              hipStream_t stream) {
  const float* x  = (const float*)d_in[0];
  const float* fc = (const float*)d_in[1];
  const float* Wq = (const float*)d_in[2];
  const float* Wk = (const float*)d_in[3];
  const float* Wv = (const float*)d_in[4];
  const float* Wo = (const float*)d_in[5];
  float* out = (float*)d_out;

  char* ws = (char*)d_ws;
  size_t off = 0;
  auto alloc = [&](size_t bytes) { char* p = ws + off; off += bytes; return p; };
  bf16_t* xb   = (bf16_t*)alloc((size_t)8192 * 2048 * 2);   // also reused as Vt after GEMMs
  bf16_t* Wqb  = (bf16_t*)alloc((size_t)2048 * 2048 * 2);
  bf16_t* Wkvb = (bf16_t*)alloc((size_t)1024 * 2048 * 2);   // Wk rows then Wv rows
  bf16_t* Wob  = (bf16_t*)alloc((size_t)2048 * 2048 * 2);
  bf16_t* Qb   = (bf16_t*)alloc((size_t)8192 * 2048 * 2);
  bf16_t* KVb  = (bf16_t*)alloc((size_t)8192 * 1024 * 2);   // [t][ K(512) | V(512) ]
  bf16_t* Ab   = (bf16_t*)alloc((size_t)8192 * 2048 * 2);
  bf16_t* Vtb  = xb;  // 8.4 MB transposed V, aliases xb (dead after GEMMs)
  (void)ws_size; (void)in_sizes; (void)n_in; (void)out_size;

  cvt_f32_bf16<<<16384, 256, 0, stream>>>(x,  xb,  4194304);
  cvt_f32_bf16<<<4096,  256, 0, stream>>>(Wq, Wqb, 1048576);
  cvt_f32_bf16<<<1024,  256, 0, stream>>>(Wk, Wkvb, 262144);
  cvt_f32_bf16<<<1024,  256, 0, stream>>>(Wv, Wkvb + (size_t)512 * 2048, 262144);
  cvt_f32_bf16<<<4096,  256, 0, stream>>>(Wo, Wob, 1048576);

  dim3 gq(16, 64), gkv(8, 64);
  gemm_bt<false><<<gq,  256, 0, stream>>>(xb, Wqb,  Qb,  8192, 2048, 2048);
  gemm_bt<false><<<gkv, 256, 0, stream>>>(xb, Wkvb, KVb, 8192, 1024, 2048);

  rope_kernel<<<32768, 256, 0, stream>>>(Qb,  fc, 4, 2048);  // Q: 16 heads
  rope_kernel<<<8192,  256, 0, stream>>>(KVb, fc, 2, 1024);  // K: 4 heads (cols 0..511)

  transpose_v<<<dim3(128, 8), 256, 0, stream>>>(KVb, Vtb);   // xb dead from here on

  attn_kernel<<<dim3(8, 64), 256, 0, stream>>>(Qb, KVb, Vtb, Ab);

  gemm_bt<true><<<gq, 256, 0, stream>>>(Ab, Wob, out, 8192, 2048, 2048);
}

// Round 3
// 462.226 us; speedup vs baseline: 2.6298x; 1.1836x over previous
//
#include <hip/hip_runtime.h>
#include <hip/hip_bf16.h>
#include <stdint.h>

typedef __bf16 bf16_t;
typedef __bf16 bf16x4 __attribute__((ext_vector_type(4)));
typedef __bf16 bf16x8 __attribute__((ext_vector_type(8)));
typedef float f32x4 __attribute__((ext_vector_type(4)));

__device__ __forceinline__ float fast_exp2(float x) {
#if __has_builtin(__builtin_amdgcn_exp2f)
  return __builtin_amdgcn_exp2f(x);
#else
  return exp2f(x);
#endif
}

// ---------------- f32 -> bf16 convert (float4 vectorized) ----------------
__global__ void cvt_f32_bf16(const float* __restrict__ in, bf16_t* __restrict__ out, int n4) {
  int i = blockIdx.x * blockDim.x + threadIdx.x;
  if (i >= n4) return;
  float4 v = ((const float4*)in)[i];
  bf16x4 o = { (bf16_t)v.x, (bf16_t)v.y, (bf16_t)v.z, (bf16_t)v.w };
  *(bf16x4*)(out + (size_t)i * 4) = o;
}

// ---------------- async global->LDS, 16B per lane ----------------
__device__ __forceinline__ void async_load16(const bf16_t* g, bf16_t* l) {
#if __has_builtin(__builtin_amdgcn_global_load_lds)
  __builtin_amdgcn_global_load_lds((const __attribute__((address_space(1))) void*)g,
                                   (__attribute__((address_space(3))) void*)l, 16, 0, 0);
#else
  *(bf16x8*)l = *(const bf16x8*)g;
#endif
}

// ---------------- GEMM: C[M,N] = A[M,K] @ B[N,K]^T ----------------
// 128x128 tile, 4 waves (2x2), BK=64, XOR-chunk-swizzled LDS (conflict-free frag reads).
// LDS row = 64 elems (128 B); chunk c of row holds global chunk c ^ (row&7).
template<bool F32OUT>
__global__ __launch_bounds__(256) void gemm_bt(const bf16_t* __restrict__ A,
                                               const bf16_t* __restrict__ B,
                                               void* __restrict__ C,
                                               int M, int N, int K) {
  __shared__ bf16_t Alds[128 * 64];
  __shared__ bf16_t Blds[128 * 64];
  const int tid = threadIdx.x;
  const int wave = tid >> 6, lane = tid & 63;
  const int lrow = lane & 15, quad = lane >> 4;
  const int wr = wave >> 1, wc = wave & 1;
  const int bm = blockIdx.y, bn = blockIdx.x;
  const bf16_t* Ab = A + (size_t)bm * 128 * K;
  const bf16_t* Bb = B + (size_t)bn * 128 * K;
  const int r0 = tid >> 3;                     // 0..31 (row within 32-row pass)
  const int c0 = ((tid & 7) ^ (r0 & 7)) << 3;  // swizzled source column (elems)
  f32x4 acc[4][4] = {};

  for (int kk = 0; kk < K; kk += 64) {
#pragma unroll
    for (int p = 0; p < 4; ++p) {
      async_load16(Ab + (size_t)(p * 32 + r0) * K + kk + c0, &Alds[(p * 256 + tid) * 8]);
      async_load16(Bb + (size_t)(p * 32 + r0) * K + kk + c0, &Blds[(p * 256 + tid) * 8]);
    }
    __syncthreads();
#pragma unroll
    for (int ks2 = 0; ks2 < 2; ++ks2) {
      const int rc = ((ks2 * 4 + quad) ^ (lrow & 7)) << 3;  // swizzled read column
      bf16x8 af[4], bfv[4];
#pragma unroll
      for (int mt = 0; mt < 4; ++mt)
        af[mt] = *(const bf16x8*)&Alds[(wr * 64 + mt * 16 + lrow) * 64 + rc];
#pragma unroll
      for (int nt = 0; nt < 4; ++nt)
        bfv[nt] = *(const bf16x8*)&Blds[(wc * 64 + nt * 16 + lrow) * 64 + rc];
#pragma unroll
      for (int mt = 0; mt < 4; ++mt)
#pragma unroll
        for (int nt = 0; nt < 4; ++nt)
          acc[mt][nt] = __builtin_amdgcn_mfma_f32_16x16x32_bf16(af[mt], bfv[nt], acc[mt][nt], 0, 0, 0);
    }
    __syncthreads();
  }

#pragma unroll
  for (int mt = 0; mt < 4; ++mt)
#pragma unroll
    for (int nt = 0; nt < 4; ++nt)
#pragma unroll
      for (int r = 0; r < 4; ++r) {
        int row = bm * 128 + wr * 64 + mt * 16 + quad * 4 + r;
        int col = bn * 128 + wc * 64 + nt * 16 + lrow;
        if (F32OUT) ((float*)C)[(size_t)row * N + col] = acc[mt][nt][r];
        else        ((bf16_t*)C)[(size_t)row * N + col] = (bf16_t)acc[mt][nt][r];
      }
}

// ---------------- RoPE (in-place, layout (rows, nheads, 128), row stride param) ----------
__global__ void rope_kernel(bf16_t* __restrict__ X, const float* __restrict__ F,
                            int hshift, int stride) {
  int i = blockIdx.x * blockDim.x + threadIdx.x;
  int d = i & 63;
  int h = (i >> 6) & ((1 << hshift) - 1);
  int row = i >> (6 + hshift);
  int t = row & 2047;
  float c = F[t * 128 + d * 2];
  float s = F[t * 128 + d * 2 + 1];
  size_t base = (size_t)row * stride + h * 128 + d;
  float q0 = (float)X[base];
  float q1 = (float)X[base + 64];
  X[base]      = (bf16_t)(q0 * c - q1 * s);
  X[base + 64] = (bf16_t)(q1 * c + q0 * s);
}

// ---- V transpose: QKV[t][2560 + kvh*128 + d] -> Vt[(b*4+kvh)*128+d][t(2048)] ----
__global__ __launch_bounds__(256) void transpose_v(const bf16_t* __restrict__ KV,
                                                   bf16_t* __restrict__ Vt) {
  __shared__ bf16_t tile[64][72];
  const int tid = threadIdx.x;
  const int t0 = blockIdx.x * 64;
  const int c0 = blockIdx.y * 64;
#pragma unroll
  for (int p = 0; p < 4; ++p) {
    int idx = p * 256 + tid;
    int r = idx >> 4, c4 = (idx & 15) * 4;
    *(bf16x4*)&tile[r][c4] = *(const bf16x4*)&KV[(size_t)(t0 + r) * 3072 + 2560 + c0 + c4];
  }
  __syncthreads();
  const int bb = t0 >> 11, t0b = t0 & 2047;
#pragma unroll
  for (int p = 0; p < 4; ++p) {
    int idx = p * 256 + tid;
    int cr = idx >> 4, t4 = (idx & 15) * 4;
    int c = c0 + cr;
    int R = (bb * 4 + (c >> 7)) * 128 + (c & 127);
    bf16x4 o;
#pragma unroll
    for (int j = 0; j < 4; ++j) o[j] = tile[t4 + j][cr];
    *(bf16x4*)&Vt[(size_t)R * 2048 + t0b + t4] = o;
  }
}

// ---------------- Flash attention, causal, GQA 16q/4kv, D=128 ----------------
// Q read from fused QKV (stride 3072) with RoPE applied on the fly (thread holds d and d+64
// as chunks ks and ks+2). S^T = mfma(A=K,B=Q); softmax rows reduce with 2 shuffles;
// P packed b64 to LDS; O += mfma(A=P, B=V^T). K/V^T staged via global_load_lds w=16,
// XOR chunk swizzle. Blocks pair q-tiles (qt, 15-qt) -> uniform 36 K-tiles per block.
__global__ __launch_bounds__(256, 2) void attn_kernel(const bf16_t* __restrict__ QKV,
                                                      const float* __restrict__ F,
                                                      const bf16_t* __restrict__ Vt,
                                                      bf16_t* __restrict__ O) {
  __shared__ bf16_t Ks[64 * 128];   // [key][d], chunk-swizzled
  __shared__ bf16_t Vs[128 * 64];   // [d][key], chunk-swizzled
  __shared__ bf16_t Ps[4 * 32 * 72];
  const int tid = threadIdx.x;
  const int wave = tid >> 6, lane = tid & 63;
  const int lrow = lane & 15, quad = lane >> 4;
  const int bh = blockIdx.y, b = bh >> 4, h = bh & 15, kvh = h >> 2;
  const size_t qoff  = ((size_t)b * 2048) * 3072 + (size_t)h * 128;
  const size_t koff  = ((size_t)b * 2048) * 3072 + 2048 + (size_t)kvh * 128;
  const size_t vtoff = ((size_t)(b * 4 + kvh) * 128) * 2048;
  const float qsc = 0.08838834764831845f * 1.44269504088896340736f;  // 1/sqrt(128)*log2(e)
  bf16_t* Pw = Ps + wave * (32 * 72);
  const float2* F2 = (const float2*)F;  // [t][64] (cos,sin)

  const int krow_l = tid >> 4;                   // 0..15
  const int kdc    = (tid & 15) ^ (krow_l & 7);  // K chunk swizzle
  const int vrow_l = tid >> 3;                   // 0..31
  const int vkc    = (tid & 7) ^ (vrow_l & 7);   // V chunk swizzle

  for (int phase = 0; phase < 2; ++phase) {
    const int qt = phase ? (15 - blockIdx.x) : blockIdx.x;
    const int qbase = qt * 128 + wave * 32;

    // Q B-frags with fused RoPE + scale: B[n=q][k=d]
    bf16x8 qf[2][4];
#pragma unroll
    for (int nt2 = 0; nt2 < 2; ++nt2) {
      const int t = qbase + nt2 * 16 + lrow;  // 0..2047
      const bf16_t* qp = QKV + qoff + (size_t)t * 3072 + quad * 8;
      bf16x8 raw[4];
#pragma unroll
      for (int ks = 0; ks < 4; ++ks) raw[ks] = *(const bf16x8*)(qp + ks * 32);
#pragma unroll
      for (int ks2 = 0; ks2 < 2; ++ks2) {
        bf16x8 lo, hi;
#pragma unroll
        for (int j = 0; j < 8; ++j) {
          int d = ks2 * 32 + quad * 8 + j;  // < 64
          float2 cs = F2[t * 64 + d];
          float q0 = (float)raw[ks2][j], q1 = (float)raw[ks2 + 2][j];
          lo[j] = (bf16_t)((q0 * cs.x - q1 * cs.y) * qsc);
          hi[j] = (bf16_t)((q1 * cs.x + q0 * cs.y) * qsc);
        }
        qf[nt2][ks2]     = lo;
        qf[nt2][ks2 + 2] = hi;
      }
    }

    f32x4 Oacc[2][8] = {};
    float m_r[2] = {-1.0e30f, -1.0e30f};
    float l_r[2] = {0.f, 0.f};
    const int kt_end = 2 * qt + 2;

    for (int kt = 0; kt < kt_end; ++kt) {
      __syncthreads();  // previous tile's LDS reads drained
      const bf16_t* Kg = QKV + koff + (size_t)(kt * 64) * 3072;
      const bf16_t* Vg = Vt + vtoff + kt * 64;
#pragma unroll
      for (int c4 = 0; c4 < 4; ++c4) {
        int ci = c4 * 256 + tid;
        async_load16(Kg + (size_t)(c4 * 16 + krow_l) * 3072 + kdc * 8, &Ks[ci * 8]);
        async_load16(Vg + (size_t)(c4 * 32 + vrow_l) * 2048 + vkc * 8, &Vs[ci * 8]);
      }
      __syncthreads();  // staging complete

      if (kt * 64 <= qbase + 31) {  // wave-uniform skip of fully-masked tiles
        // S^T = K Q^T : C[m=key][n=q]
        f32x4 S[2][4] = {};
#pragma unroll
        for (int ks = 0; ks < 4; ++ks) {
          bf16x8 kf[4];
#pragma unroll
          for (int mt = 0; mt < 4; ++mt) {
            int dc = (ks * 4 + quad) ^ (lrow & 7);
            kf[mt] = *(const bf16x8*)&Ks[(mt * 16 + lrow) * 128 + dc * 8];
          }
#pragma unroll
          for (int nt2 = 0; nt2 < 2; ++nt2)
#pragma unroll
            for (int mt = 0; mt < 4; ++mt)
              S[nt2][mt] = __builtin_amdgcn_mfma_f32_16x16x32_bf16(kf[mt], qf[nt2][ks], S[nt2][mt], 0, 0, 0);
        }
        // causal mask (diagonal tiles only). S^T: key=row, q=col.
        if (kt * 64 + 63 > qbase) {
#pragma unroll
          for (int nt2 = 0; nt2 < 2; ++nt2) {
            int q = qbase + nt2 * 16 + lrow;
#pragma unroll
            for (int mt = 0; mt < 4; ++mt) {
              int key0 = kt * 64 + mt * 16 + quad * 4;
#pragma unroll
              for (int r = 0; r < 4; ++r)
                if (key0 + r > q) S[nt2][mt][r] = -1.0e30f;
            }
          }
        }
        // online softmax (log2 domain), rows reduce across quads: 2 shuffles
        float alpha[2];
#pragma unroll
        for (int nt2 = 0; nt2 < 2; ++nt2) {
          float mx = -1.0e30f;
#pragma unroll
          for (int mt = 0; mt < 4; ++mt)
#pragma unroll
            for (int r = 0; r < 4; ++r) mx = fmaxf(mx, S[nt2][mt][r]);
          mx = fmaxf(mx, __shfl_xor(mx, 16, 64));
          mx = fmaxf(mx, __shfl_xor(mx, 32, 64));
          float mnew = fmaxf(m_r[nt2], mx);
          alpha[nt2] = fast_exp2(m_r[nt2] - mnew);
          m_r[nt2] = mnew;
          float rs = 0.f;
#pragma unroll
          for (int mt = 0; mt < 4; ++mt) {
            bf16x4 pk;
#pragma unroll
            for (int r = 0; r < 4; ++r) {
              float p = fast_exp2(S[nt2][mt][r] - mnew);
              rs += p;
              pk[r] = (bf16_t)p;
            }
            *(bf16x4*)&Pw[(nt2 * 16 + lrow) * 72 + mt * 16 + quad * 4] = pk;
          }
          rs += __shfl_xor(rs, 16, 64);
          rs += __shfl_xor(rs, 32, 64);
          l_r[nt2] = l_r[nt2] * alpha[nt2] + rs;
        }
        // lazy O rescale
        bool nz = (alpha[0] != 1.f) || (alpha[1] != 1.f);
        if (__ballot(nz) != 0ull) {
#pragma unroll
          for (int mt2 = 0; mt2 < 2; ++mt2)
#pragma unroll
            for (int r = 0; r < 4; ++r) {
              float av = __shfl(alpha[mt2], quad * 4 + r, 16);
#pragma unroll
              for (int dt = 0; dt < 8; ++dt) Oacc[mt2][dt][r] *= av;
            }
        }
        // O += P V : A=P from Pw, B=V^T from Vs (swizzled)
#pragma unroll
        for (int ks2 = 0; ks2 < 2; ++ks2) {
          bf16x8 ap[2];
#pragma unroll
          for (int mt2 = 0; mt2 < 2; ++mt2)
            ap[mt2] = *(const bf16x8*)&Pw[(mt2 * 16 + lrow) * 72 + ks2 * 32 + quad * 8];
          int dc = (ks2 * 4 + quad) ^ (lrow & 7);
#pragma unroll
          for (int dt = 0; dt < 8; ++dt) {
            bf16x8 bv = *(const bf16x8*)&Vs[(dt * 16 + lrow) * 64 + dc * 8];
#pragma unroll
            for (int mt2 = 0; mt2 < 2; ++mt2)
              Oacc[mt2][dt] = __builtin_amdgcn_mfma_f32_16x16x32_bf16(ap[mt2], bv, Oacc[mt2][dt], 0, 0, 0);
          }
        }
      }
    }

    // epilogue: O /= l, store bf16
#pragma unroll
    for (int mt2 = 0; mt2 < 2; ++mt2)
#pragma unroll
      for (int r = 0; r < 4; ++r) {
        float lv = __shfl(l_r[mt2], quad * 4 + r, 16);
        float inv = 1.0f / lv;
        int row = qbase + mt2 * 16 + quad * 4 + r;
#pragma unroll
        for (int dt = 0; dt < 8; ++dt)
          O[(size_t)(bh >> 4) * 2048 * 2048 + (size_t)row * 2048 + (bh & 15) * 128 + dt * 16 + lrow] =
              (bf16_t)(Oacc[mt2][dt][r] * inv);
      }
  }
}

// ---------------- launch ----------------
extern "C" void kernel_launch(void* const* d_in, const int* in_sizes, int n_in,
                              void* d_out, int out_size, void* d_ws, size_t ws_size,
                              hipStream_t stream) {
  const float* x  = (const float*)d_in[0];
  const float* fc = (const float*)d_in[1];
  const float* Wq = (const float*)d_in[2];
  const float* Wk = (const float*)d_in[3];
  const float* Wv = (const float*)d_in[4];
  const float* Wo = (const float*)d_in[5];
  float* out = (float*)d_out;

  char* ws = (char*)d_ws;
  size_t off = 0;
  auto alloc = [&](size_t bytes) { char* p = ws + off; off += bytes; return p; };
  bf16_t* xb    = (bf16_t*)alloc((size_t)8192 * 2048 * 2);  // reused as Vt after QKV GEMM
  bf16_t* Wqkvb = (bf16_t*)alloc((size_t)3072 * 2048 * 2);  // [Wq; Wk; Wv] rows
  bf16_t* Wob   = (bf16_t*)alloc((size_t)2048 * 2048 * 2);
  bf16_t* QKVb  = (bf16_t*)alloc((size_t)8192 * 3072 * 2);  // [t][ Q(2048) | K(512) | V(512) ]
  bf16_t* Ab    = (bf16_t*)alloc((size_t)8192 * 2048 * 2);
  bf16_t* Vtb   = xb;  // transposed V aliases xb (dead after QKV GEMM)
  (void)ws_size; (void)in_sizes; (void)n_in; (void)out_size;

  cvt_f32_bf16<<<16384, 256, 0, stream>>>(x,  xb, 4194304);
  cvt_f32_bf16<<<4096,  256, 0, stream>>>(Wq, Wqkvb, 1048576);
  cvt_f32_bf16<<<1024,  256, 0, stream>>>(Wk, Wqkvb + (size_t)2048 * 2048, 262144);
  cvt_f32_bf16<<<1024,  256, 0, stream>>>(Wv, Wqkvb + (size_t)2560 * 2048, 262144);
  cvt_f32_bf16<<<4096,  256, 0, stream>>>(Wo, Wob, 1048576);

  // fused QKV projection: C[8192][3072]
  gemm_bt<false><<<dim3(24, 64), 256, 0, stream>>>(xb, Wqkvb, QKVb, 8192, 3072, 2048);

  // RoPE on K only (Q rope fused into attention); K cols 2048..2559, stride 3072
  rope_kernel<<<8192, 256, 0, stream>>>(QKVb + 2048, fc, 2, 3072);

  transpose_v<<<dim3(128, 8), 256, 0, stream>>>(QKVb, Vtb);  // xb dead from here

  attn_kernel<<<dim3(8, 64), 256, 0, stream>>>(QKVb, fc, Vtb, Ab);

  gemm_bt<true><<<dim3(16, 64), 256, 0, stream>>>(Ab, Wob, out, 8192, 2048, 2048);
}

// Round 4
// 460.719 us; speedup vs baseline: 2.6384x; 1.0033x over previous
//
#include <hip/hip_runtime.h>
#include <hip/hip_bf16.h>
#include <stdint.h>

typedef __bf16 bf16_t;
typedef __bf16 bf16x4 __attribute__((ext_vector_type(4)));
typedef __bf16 bf16x8 __attribute__((ext_vector_type(8)));
typedef float f32x4 __attribute__((ext_vector_type(4)));

__device__ __forceinline__ float fast_exp2(float x) {
#if __has_builtin(__builtin_amdgcn_exp2f)
  return __builtin_amdgcn_exp2f(x);
#else
  return exp2f(x);
#endif
}

// ---------------- fused f32 -> bf16 convert, all 5 tensors in one dispatch ------------
// regions (in 256-f4 blocks): x 16384 | Wq 4096 | Wk 1024 | Wv 1024 | Wo 4096 = 26624
__global__ void cvt_all(const float* __restrict__ x,  const float* __restrict__ Wq,
                        const float* __restrict__ Wk, const float* __restrict__ Wv,
                        const float* __restrict__ Wo, bf16_t* __restrict__ xb,
                        bf16_t* __restrict__ wqkv, bf16_t* __restrict__ wob) {
  const int bid = blockIdx.x, tid = threadIdx.x;
  const float* src; bf16_t* dst; int i;
  if (bid < 16384)      { src = x;  dst = xb;             i = bid * 256 + tid; }
  else if (bid < 20480) { src = Wq; dst = wqkv;           i = (bid - 16384) * 256 + tid; }
  else if (bid < 21504) { src = Wk; dst = wqkv + 4194304; i = (bid - 20480) * 256 + tid; }
  else if (bid < 22528) { src = Wv; dst = wqkv + 5242880; i = (bid - 21504) * 256 + tid; }
  else                  { src = Wo; dst = wob;            i = (bid - 22528) * 256 + tid; }
  float4 v = ((const float4*)src)[i];
  bf16x4 o = { (bf16_t)v.x, (bf16_t)v.y, (bf16_t)v.z, (bf16_t)v.w };
  *(bf16x4*)(dst + (size_t)i * 4) = o;
}

// ---------------- async global->LDS, 16B per lane ----------------
__device__ __forceinline__ void async_load16(const bf16_t* g, bf16_t* l) {
#if __has_builtin(__builtin_amdgcn_global_load_lds)
  __builtin_amdgcn_global_load_lds((const __attribute__((address_space(1))) void*)g,
                                   (__attribute__((address_space(3))) void*)l, 16, 0, 0);
#else
  *(bf16x8*)l = *(const bf16x8*)g;
#endif
}

// ---------------- GEMM: C[M,N] = A[M,K] @ B[N,K]^T ----------------
// 128x128 tile, 4 waves (2x2), BK=64, XOR-chunk-swizzled LDS (conflict-free, 0 measured).
// VSPLIT: output cols >= 2560 (bn >= 20) are V -> stored transposed into Vt
// [(b*4+kvh)*128+d][t]; C then uses ldc=2560.
template<bool F32OUT, bool VSPLIT>
__global__ __launch_bounds__(256) void gemm_bt(const bf16_t* __restrict__ A,
                                               const bf16_t* __restrict__ B,
                                               void* __restrict__ C,
                                               bf16_t* __restrict__ Vt,
                                               int M, int N, int K, int ldc) {
  __shared__ bf16_t Alds[128 * 64];
  __shared__ bf16_t Blds[128 * 64];
  const int tid = threadIdx.x;
  const int wave = tid >> 6, lane = tid & 63;
  const int lrow = lane & 15, quad = lane >> 4;
  const int wr = wave >> 1, wc = wave & 1;
  const int bm = blockIdx.y, bn = blockIdx.x;
  const bf16_t* Ab = A + (size_t)bm * 128 * K;
  const bf16_t* Bb = B + (size_t)bn * 128 * K;
  const int r0 = tid >> 3;
  const int c0 = ((tid & 7) ^ (r0 & 7)) << 3;
  f32x4 acc[4][4] = {};

  for (int kk = 0; kk < K; kk += 64) {
#pragma unroll
    for (int p = 0; p < 4; ++p) {
      async_load16(Ab + (size_t)(p * 32 + r0) * K + kk + c0, &Alds[(p * 256 + tid) * 8]);
      async_load16(Bb + (size_t)(p * 32 + r0) * K + kk + c0, &Blds[(p * 256 + tid) * 8]);
    }
    __syncthreads();
#pragma unroll
    for (int ks2 = 0; ks2 < 2; ++ks2) {
      const int rc = ((ks2 * 4 + quad) ^ (lrow & 7)) << 3;
      bf16x8 af[4], bfv[4];
#pragma unroll
      for (int mt = 0; mt < 4; ++mt)
        af[mt] = *(const bf16x8*)&Alds[(wr * 64 + mt * 16 + lrow) * 64 + rc];
#pragma unroll
      for (int nt = 0; nt < 4; ++nt)
        bfv[nt] = *(const bf16x8*)&Blds[(wc * 64 + nt * 16 + lrow) * 64 + rc];
#pragma unroll
      for (int mt = 0; mt < 4; ++mt)
#pragma unroll
        for (int nt = 0; nt < 4; ++nt)
          acc[mt][nt] = __builtin_amdgcn_mfma_f32_16x16x32_bf16(af[mt], bfv[nt], acc[mt][nt], 0, 0, 0);
    }
    __syncthreads();
  }

  if (VSPLIT && bn >= 20) {
    // V columns: store transposed. col-2560 = kvh*128+d; Vt[(b*4+kvh)*128+d][t]
#pragma unroll
    for (int mt = 0; mt < 4; ++mt)
#pragma unroll
      for (int nt = 0; nt < 4; ++nt) {
        int row = bm * 128 + wr * 64 + mt * 16 + quad * 4;      // t (4 consecutive)
        int cv  = bn * 128 + wc * 64 + nt * 16 + lrow - 2560;   // kvh*128+d
        int b = row >> 11, tl = row & 2047;
        bf16x4 o;
#pragma unroll
        for (int r = 0; r < 4; ++r) o[r] = (bf16_t)acc[mt][nt][r];
        *(bf16x4*)&Vt[((size_t)(b * 512 + cv)) * 2048 + tl] = o;
      }
    return;
  }
#pragma unroll
  for (int mt = 0; mt < 4; ++mt)
#pragma unroll
    for (int nt = 0; nt < 4; ++nt)
#pragma unroll
      for (int r = 0; r < 4; ++r) {
        int row = bm * 128 + wr * 64 + mt * 16 + quad * 4 + r;
        int col = bn * 128 + wc * 64 + nt * 16 + lrow;
        if (F32OUT) ((float*)C)[(size_t)row * ldc + col] = acc[mt][nt][r];
        else        ((bf16_t*)C)[(size_t)row * ldc + col] = (bf16_t)acc[mt][nt][r];
      }
}

// ---------------- RoPE (in-place, layout (rows, nheads, 128), row stride param) ----------
__global__ void rope_kernel(bf16_t* __restrict__ X, const float* __restrict__ F,
                            int hshift, int stride) {
  int i = blockIdx.x * blockDim.x + threadIdx.x;
  int d = i & 63;
  int h = (i >> 6) & ((1 << hshift) - 1);
  int row = i >> (6 + hshift);
  int t = row & 2047;
  float c = F[t * 128 + d * 2];
  float s = F[t * 128 + d * 2 + 1];
  size_t base = (size_t)row * stride + h * 128 + d;
  float q0 = (float)X[base];
  float q1 = (float)X[base + 64];
  X[base]      = (bf16_t)(q0 * c - q1 * s);
  X[base + 64] = (bf16_t)(q1 * c + q0 * s);
}

// ---------------- Flash attention, causal, GQA 16q/4kv, D=128 ----------------
// Software-pipelined: K/V double-buffered in LDS; ONE __syncthreads per K-tile; the DMA
// for tile kt+1 is issued right after the barrier and flies during compute of tile kt
// (vmcnt(0) drain at the next barrier only waits for residual latency). Ps is XOR-chunk
// swizzled (no padding) so total LDS = 32K(K) + 32K(V) + 16K(P) = 80 KB -> 2 blocks/CU.
__global__ __launch_bounds__(256, 2) void attn_kernel(const bf16_t* __restrict__ QKV,
                                                      const float* __restrict__ F,
                                                      const bf16_t* __restrict__ Vt,
                                                      bf16_t* __restrict__ O) {
  __shared__ bf16_t Ks[2][64 * 128];   // [buf][key][d], chunk-swizzled
  __shared__ bf16_t Vs[2][128 * 64];   // [buf][d][key], chunk-swizzled
  __shared__ bf16_t Ps[4 * 32 * 64];   // per-wave, chunk-swizzled
  const int tid = threadIdx.x;
  const int wave = tid >> 6, lane = tid & 63;
  const int lrow = lane & 15, quad = lane >> 4;
  const int bh = blockIdx.y, b = bh >> 4, h = bh & 15, kvh = h >> 2;
  const size_t qoff  = ((size_t)b * 2048) * 2560 + (size_t)h * 128;
  const size_t koff  = ((size_t)b * 2048) * 2560 + 2048 + (size_t)kvh * 128;
  const size_t vtoff = ((size_t)(b * 4 + kvh) * 128) * 2048;
  const float qsc = 0.08838834764831845f * 1.44269504088896340736f;  // 1/sqrt(128)*log2(e)
  bf16_t* Pw = Ps + wave * (32 * 64);
  const float2* F2 = (const float2*)F;  // [t][64] (cos,sin)

  const int krow_l = tid >> 4;                   // 0..15
  const int kdc    = (tid & 15) ^ (krow_l & 7);  // K chunk swizzle
  const int vrow_l = tid >> 3;                   // 0..31
  const int vkc    = (tid & 7) ^ (vrow_l & 7);   // V chunk swizzle

  auto stage = [&](int kt, int bsel) {
    const bf16_t* Kg = QKV + koff + (size_t)(kt * 64) * 2560;
    const bf16_t* Vg = Vt + vtoff + kt * 64;
    bf16_t* Kd = &Ks[bsel][0];
    bf16_t* Vd = &Vs[bsel][0];
#pragma unroll
    for (int c4 = 0; c4 < 4; ++c4) {
      int ci = c4 * 256 + tid;
      async_load16(Kg + (size_t)(c4 * 16 + krow_l) * 2560 + kdc * 8, Kd + ci * 8);
      async_load16(Vg + (size_t)(c4 * 32 + vrow_l) * 2048 + vkc * 8, Vd + ci * 8);
    }
  };

  for (int phase = 0; phase < 2; ++phase) {
    const int qt = phase ? (15 - blockIdx.x) : blockIdx.x;
    const int qbase = qt * 128 + wave * 32;

    // Q B-frags with fused RoPE + scale: B[n=q][k=d]
    bf16x8 qf[2][4];
#pragma unroll
    for (int nt2 = 0; nt2 < 2; ++nt2) {
      const int t = qbase + nt2 * 16 + lrow;  // 0..2047
      const bf16_t* qp = QKV + qoff + (size_t)t * 2560 + quad * 8;
      bf16x8 raw[4];
#pragma unroll
      for (int ks = 0; ks < 4; ++ks) raw[ks] = *(const bf16x8*)(qp + ks * 32);
#pragma unroll
      for (int ks2 = 0; ks2 < 2; ++ks2) {
        bf16x8 lo, hi;
#pragma unroll
        for (int j = 0; j < 8; ++j) {
          int d = ks2 * 32 + quad * 8 + j;  // < 64
          float2 cs = F2[t * 64 + d];
          float q0 = (float)raw[ks2][j], q1 = (float)raw[ks2 + 2][j];
          lo[j] = (bf16_t)((q0 * cs.x - q1 * cs.y) * qsc);
          hi[j] = (bf16_t)((q1 * cs.x + q0 * cs.y) * qsc);
        }
        qf[nt2][ks2]     = lo;
        qf[nt2][ks2 + 2] = hi;
      }
    }

    f32x4 Oacc[2][8] = {};
    float m_r[2] = {-1.0e30f, -1.0e30f};
    float l_r[2] = {0.f, 0.f};
    const int kt_end = 2 * qt + 2;

    stage(0, 0);  // prime the pipeline

    for (int kt = 0; kt < kt_end; ++kt) {
      // Single barrier: (a) drains tile-kt DMA (issued last iteration) for all waves,
      // (b) guarantees no wave still reads the buffer tile kt+1 will overwrite.
      __syncthreads();
      if (kt + 1 < kt_end) stage(kt + 1, (kt + 1) & 1);
      const bf16_t* Kb_ = &Ks[kt & 1][0];
      const bf16_t* Vb_ = &Vs[kt & 1][0];

      if (kt * 64 <= qbase + 31) {  // wave-uniform skip of fully-masked tiles
        // S^T = K Q^T : C[m=key][n=q]
        f32x4 S[2][4] = {};
#pragma unroll
        for (int ks = 0; ks < 4; ++ks) {
          bf16x8 kf[4];
#pragma unroll
          for (int mt = 0; mt < 4; ++mt) {
            int dc = (ks * 4 + quad) ^ (lrow & 7);
            kf[mt] = *(const bf16x8*)&Kb_[(mt * 16 + lrow) * 128 + dc * 8];
          }
#pragma unroll
          for (int nt2 = 0; nt2 < 2; ++nt2)
#pragma unroll
            for (int mt = 0; mt < 4; ++mt)
              S[nt2][mt] = __builtin_amdgcn_mfma_f32_16x16x32_bf16(kf[mt], qf[nt2][ks], S[nt2][mt], 0, 0, 0);
        }
        // causal mask (diagonal tiles only). S^T: key=row, q=col.
        if (kt * 64 + 63 > qbase) {
#pragma unroll
          for (int nt2 = 0; nt2 < 2; ++nt2) {
            int q = qbase + nt2 * 16 + lrow;
#pragma unroll
            for (int mt = 0; mt < 4; ++mt) {
              int key0 = kt * 64 + mt * 16 + quad * 4;
#pragma unroll
              for (int r = 0; r < 4; ++r)
                if (key0 + r > q) S[nt2][mt][r] = -1.0e30f;
            }
          }
        }
        // online softmax (log2 domain); P -> Pw with chunk swizzle
        float alpha[2];
#pragma unroll
        for (int nt2 = 0; nt2 < 2; ++nt2) {
          float mx = -1.0e30f;
#pragma unroll
          for (int mt = 0; mt < 4; ++mt)
#pragma unroll
            for (int r = 0; r < 4; ++r) mx = fmaxf(mx, S[nt2][mt][r]);
          mx = fmaxf(mx, __shfl_xor(mx, 16, 64));
          mx = fmaxf(mx, __shfl_xor(mx, 32, 64));
          float mnew = fmaxf(m_r[nt2], mx);
          alpha[nt2] = fast_exp2(m_r[nt2] - mnew);
          m_r[nt2] = mnew;
          float rs = 0.f;
          const int prow = nt2 * 16 + lrow;
          const int pbase = prow * 64 + ((quad & 1) << 2);
#pragma unroll
          for (int mt = 0; mt < 4; ++mt) {
            bf16x4 pk;
#pragma unroll
            for (int r = 0; r < 4; ++r) {
              float p = fast_exp2(S[nt2][mt][r] - mnew);
              rs += p;
              pk[r] = (bf16_t)p;
            }
            int c8 = ((mt * 2 + (quad >> 1)) ^ (prow & 7)) << 3;
            *(bf16x4*)&Pw[pbase + c8] = pk;
          }
          rs += __shfl_xor(rs, 16, 64);
          rs += __shfl_xor(rs, 32, 64);
          l_r[nt2] = l_r[nt2] * alpha[nt2] + rs;
        }
        // lazy O rescale
        bool nz = (alpha[0] != 1.f) || (alpha[1] != 1.f);
        if (__ballot(nz) != 0ull) {
#pragma unroll
          for (int mt2 = 0; mt2 < 2; ++mt2)
#pragma unroll
            for (int r = 0; r < 4; ++r) {
              float av = __shfl(alpha[mt2], quad * 4 + r, 16);
#pragma unroll
              for (int dt = 0; dt < 8; ++dt) Oacc[mt2][dt][r] *= av;
            }
        }
        // O += P V : A=P from Pw (swizzled), B=V^T from Vs (swizzled)
#pragma unroll
        for (int ks2 = 0; ks2 < 2; ++ks2) {
          bf16x8 ap[2];
#pragma unroll
          for (int mt2 = 0; mt2 < 2; ++mt2) {
            int prow = mt2 * 16 + lrow;
            ap[mt2] = *(const bf16x8*)&Pw[prow * 64 + (((ks2 * 4 + quad) ^ (prow & 7)) << 3)];
          }
          int dc = (ks2 * 4 + quad) ^ (lrow & 7);
#pragma unroll
          for (int dt = 0; dt < 8; ++dt) {
            bf16x8 bv = *(const bf16x8*)&Vb_[(dt * 16 + lrow) * 64 + dc * 8];
#pragma unroll
            for (int mt2 = 0; mt2 < 2; ++mt2)
              Oacc[mt2][dt] = __builtin_amdgcn_mfma_f32_16x16x32_bf16(ap[mt2], bv, Oacc[mt2][dt], 0, 0, 0);
          }
        }
      }
    }

    // epilogue: O /= l, store bf16 (Ab stride 2048)
#pragma unroll
    for (int mt2 = 0; mt2 < 2; ++mt2)
#pragma unroll
      for (int r = 0; r < 4; ++r) {
        float lv = __shfl(l_r[mt2], quad * 4 + r, 16);
        float inv = 1.0f / lv;
        int row = qbase + mt2 * 16 + quad * 4 + r;
#pragma unroll
        for (int dt = 0; dt < 8; ++dt)
          O[(size_t)b * 2048 * 2048 + (size_t)row * 2048 + h * 128 + dt * 16 + lrow] =
              (bf16_t)(Oacc[mt2][dt][r] * inv);
      }
  }
}

// ---------------- launch ----------------
extern "C" void kernel_launch(void* const* d_in, const int* in_sizes, int n_in,
                              void* d_out, int out_size, void* d_ws, size_t ws_size,
                              hipStream_t stream) {
  const float* x  = (const float*)d_in[0];
  const float* fc = (const float*)d_in[1];
  const float* Wq = (const float*)d_in[2];
  const float* Wk = (const float*)d_in[3];
  const float* Wv = (const float*)d_in[4];
  const float* Wo = (const float*)d_in[5];
  float* out = (float*)d_out;

  char* ws = (char*)d_ws;
  size_t off = 0;
  auto alloc = [&](size_t bytes) { char* p = ws + off; off += bytes; return p; };
  bf16_t* xb    = (bf16_t*)alloc((size_t)8192 * 2048 * 2);  // x bf16
  bf16_t* Wqkvb = (bf16_t*)alloc((size_t)3072 * 2048 * 2);  // [Wq; Wk; Wv] rows
  bf16_t* Wob   = (bf16_t*)alloc((size_t)2048 * 2048 * 2);
  bf16_t* QKVb  = (bf16_t*)alloc((size_t)8192 * 2560 * 2);  // [t][ Q(2048) | K(512) ]
  bf16_t* Ab    = (bf16_t*)alloc((size_t)8192 * 2048 * 2);
  bf16_t* Vtb   = (bf16_t*)alloc((size_t)2048 * 2048 * 2);  // V^T [(b*4+kvh)*128+d][t]
  (void)ws_size; (void)in_sizes; (void)n_in; (void)out_size;
  // total = 138,412,032 B == round-1 footprint (known to fit)

  cvt_all<<<26624, 256, 0, stream>>>(x, Wq, Wk, Wv, Wo, xb, Wqkvb, Wob);

  // fused QKV projection; V columns stored transposed into Vtb, Q|K into QKVb (ldc=2560)
  gemm_bt<false, true><<<dim3(24, 64), 256, 0, stream>>>(xb, Wqkvb, QKVb, Vtb,
                                                         8192, 3072, 2048, 2560);

  // RoPE on K only (Q rope fused into attention); K cols 2048..2559, stride 2560
  rope_kernel<<<8192, 256, 0, stream>>>(QKVb + 2048, fc, 2, 2560);

  attn_kernel<<<dim3(8, 64), 256, 0, stream>>>(QKVb, fc, Vtb, Ab);

  gemm_bt<true, false><<<dim3(16, 64), 256, 0, stream>>>(Ab, Wob, out, nullptr,
                                                         8192, 2048, 2048, 2048);
}